// Round 3
// baseline (180.533 us; speedup 1.0000x reference)
//
#include <hip/hip_runtime.h>
#include <hip/hip_bf16.h>

#define S_LEN 4096
#define DIM   128
#define NB    4
#define BQ    256          // q rows per block (4 waves x 64)
#define BKT   128          // k rows per chunk (CH=1: one K-tile per block)
#define NQT   (S_LEN / BQ) // 16 q tiles per batch
#define ROPE_BLKS (NB * S_LEN / 4)

typedef __bf16 bf16_t;
typedef __attribute__((ext_vector_type(8)))  __bf16       bf16x8;
typedef __attribute__((ext_vector_type(16))) float        f32x16;
typedef __attribute__((ext_vector_type(4)))  unsigned int u32x4;

#define MFMA32(a, b, c) __builtin_amdgcn_mfma_f32_32x32x16_bf16((a), (b), (c), 0, 0, 0)

// v_cvt_pk_bf16_f32: dst.lo = bf16(a), dst.hi = bf16(b)
#define CVTPK(d, a, b) asm("v_cvt_pk_bf16_f32 %0, %1, %2" : "=v"(d) : "v"(a), "v"(b))
// v_permlane32_swap_b32 vdst, vsrc: vdst HIGH lanes <-> vsrc LOW lanes (verified r2)
#define PSWAP(d, s)    asm("v_permlane32_swap_b32 %0, %1" : "+v"(d), "+v"(s))

// ---------------- fused preprocessing: RoPE(Q,K)->bf16 + V->V^T bf16 ----------------
__global__ void prep_kernel(const float* __restrict__ Q,
                            const float* __restrict__ K,
                            const float* __restrict__ V,
                            bf16_t* __restrict__ Qr,
                            bf16_t* __restrict__ Kr,
                            bf16_t* __restrict__ Vt) {
    int bid = blockIdx.x;
    int t   = threadIdx.x;
    if (bid < ROPE_BLKS) {
        int i   = t & 63;                      // freq index 0..63
        int row = bid * 4 + (t >> 6);          // global row in [0, B*S)
        int s   = row & (S_LEN - 1);
        size_t base = (size_t)row * DIM;
        float e       = -(float)i * (13.287712379549449f / 64.0f); // log2(10000)/64
        float inv_rev = exp2f(e) * 0.15915494309189535f;           // /(2*pi)
        float rev = (float)s * inv_rev;
        float fr  = rev - floorf(rev);
        float c  = __builtin_amdgcn_cosf(fr);
        float sn = __builtin_amdgcn_sinf(fr);
        float q1 = Q[base + i], q2 = Q[base + i + 64];
        float k1 = K[base + i], k2 = K[base + i + 64];
        Qr[base + i]      = (bf16_t)(q1 * c - q2 * sn);
        Qr[base + i + 64] = (bf16_t)(q2 * c + q1 * sn);
        Kr[base + i]      = (bf16_t)(k1 * c - k2 * sn);
        Kr[base + i + 64] = (bf16_t)(k2 * c + k1 * sn);
    } else {
        int idx = bid - ROPE_BLKS;             // [0, 256)
        int b   = idx >> 6;
        int s0  = (idx & 63) * 64;
        int d   = t >> 1;
        int sh  = (t & 1) * 32;
        const float* vb = V + (size_t)b * S_LEN * DIM;
        bf16_t* ob = Vt + ((size_t)b * DIM + d) * S_LEN;
        #pragma unroll
        for (int j8 = 0; j8 < 4; ++j8) {
            bf16x8 u;
            #pragma unroll
            for (int e2 = 0; e2 < 8; ++e2) {
                int s = s0 + sh + j8 * 8 + e2;
                u[e2] = (bf16_t)vb[(size_t)s * DIM + d];
            }
            *(bf16x8*)(ob + s0 + sh + j8 * 8) = u;   // 16B store, contiguous in s
        }
    }
}

// ---------------- main: O += tril(Qr Kr^T) V , split-K chunks of 128 k ----------------
__device__ __forceinline__ unsigned swzo(int row, int colByte) {
    // 256B rows; XOR-swizzle 16B slots by (row&15) -> conflict-free b128 col reads
    return (unsigned)(row * 256 + (colByte ^ ((row & 15) << 4)));
}

__device__ __forceinline__ void cvt_swap(const f32x16& s, unsigned int w[8]) {
    CVTPK(w[0], s[0],  s[1]);  CVTPK(w[1], s[2],  s[3]);
    CVTPK(w[2], s[4],  s[5]);  CVTPK(w[3], s[6],  s[7]);
    CVTPK(w[4], s[8],  s[9]);  CVTPK(w[5], s[10], s[11]);
    CVTPK(w[6], s[12], s[13]); CVTPK(w[7], s[14], s[15]);
    // dst-high <-> src-low: {w0..w3} = A-frag k 0..15 (k=8*lg+e), {w4..w7} = k 16..31
    PSWAP(w[0], w[2]); PSWAP(w[1], w[3]);
    PSWAP(w[4], w[6]); PSWAP(w[5], w[7]);
}

__launch_bounds__(256, 2)
__global__ void attn_main_kernel(const bf16_t* __restrict__ Qr,
                                 const bf16_t* __restrict__ Kr,
                                 const bf16_t* __restrict__ Vt,
                                 float* __restrict__ Out) {
    __shared__ bf16_t Kt[128 * 128];  // 32 KB, swizzled [k][d]
    __shared__ bf16_t Vl[128 * 128];  // 32 KB, swizzled [d][k]

    // decode (batch, q-tile, chunk); uniform 1-tile chunks, big q-tiles first
    int b = blockIdx.x & 3;
    int t = blockIdx.x >> 2;
    int qt = 0, c0 = 0;
    for (int i2 = NQT - 1; i2 >= 0; --i2) {
        int n = 2 * (i2 + 1);                // K-tiles for this q-tile
        if (t < n) { qt = i2; c0 = t; break; }
        t -= n;
    }

    int tid  = threadIdx.x;
    int w    = tid >> 6;
    int lane = tid & 63;
    int lr   = lane & 31;
    int lg   = lane >> 5;

    int q0 = qt * BQ;
    int qw = q0 + w * 64;                // this wave's 64 q rows
    int kbase = c0 * BKT;

    const bf16_t* Qb = Qr + (size_t)b * S_LEN * DIM;
    const bf16_t* Kb = Kr + (size_t)b * S_LEN * DIM;
    const bf16_t* Vb = Vt + (size_t)b * DIM * S_LEN;

    // Q as MFMA-B fragments, resident in regs: [qblock][d-slice of 16]
    bf16x8 qf[2][8];
    #pragma unroll
    for (int qb = 0; qb < 2; ++qb)
        #pragma unroll
        for (int s2 = 0; s2 < 8; ++s2)
            qf[qb][s2] = *(const bf16x8*)(Qb + (size_t)(qw + qb * 32 + lr) * DIM
                                          + s2 * 16 + lg * 8);

    // stage K(RoPE'd) and V^T tiles (128x128 bf16 each), swizzled
    #pragma unroll
    for (int j = 0; j < 8; ++j) {
        int idx = tid + j * 256;
        int row = idx >> 4, slot = idx & 15;
        u32x4 kd = *(const u32x4*)(Kb + (size_t)(kbase + row) * DIM + slot * 8);
        *(u32x4*)((char*)Kt + swzo(row, slot * 16)) = kd;
        u32x4 vd = *(const u32x4*)(Vb + (size_t)row * S_LEN + kbase + slot * 8);
        *(u32x4*)((char*)Vl + swzo(row, slot * 16)) = vd;
    }

    f32x16 acc[2][4];
    #pragma unroll
    for (int qb = 0; qb < 2; ++qb)
        #pragma unroll
        for (int db = 0; db < 4; ++db)
            #pragma unroll
            for (int r = 0; r < 16; ++r) acc[qb][db][r] = 0.f;

    __syncthreads();

    // branch-free: all 4 kb sub-tiles, both q-blocks, unconditional predicated mask
    #pragma unroll
    for (int kb = 0; kb < 4; ++kb) {
        int ksub = kb * 32;
        int kmin = kbase + ksub;

        // S^T = K . Q^T  (lane holds P column q = qw + qb*32 + lr)
        f32x16 s0, s1;
        #pragma unroll
        for (int r = 0; r < 16; ++r) { s0[r] = 0.f; s1[r] = 0.f; }
        #pragma unroll
        for (int h = 0; h < 2; ++h) {       // d in two halves (VGPR economy)
            bf16x8 af[4];
            #pragma unroll
            for (int s2 = 0; s2 < 4; ++s2)
                af[s2] = *(const bf16x8*)((const char*)Kt +
                    swzo(ksub + lr, (h * 64 + s2 * 16 + lg * 8) * 2));
            #pragma unroll
            for (int s2 = 0; s2 < 4; ++s2) {
                s0 = MFMA32(af[s2], qf[0][h * 4 + s2], s0);
                s1 = MFMA32(af[s2], qf[1][h * 4 + s2], s1);
            }
        }

        // causal mask: zero k > q (C layout: col=lane&31=q, row=crow(reg)=k)
        #pragma unroll
        for (int r = 0; r < 16; ++r) {
            int kg = kmin + (r & 3) + ((r >> 2) << 3) + (lg << 2);
            s0[r] = (kg > qw + lr)      ? 0.f : s0[r];
            s1[r] = (kg > qw + 32 + lr) ? 0.f : s1[r];
        }

        // P -> bf16 A-fragments via cvt_pk + permlane32_swap (no LDS trip)
        unsigned int w0[8], w1[8];
        cvt_swap(s0, w0);
        cvt_swap(s1, w1);
        u32x4 t00 = {w0[0], w0[1], w0[2], w0[3]};
        u32x4 t01 = {w0[4], w0[5], w0[6], w0[7]};
        u32x4 t10 = {w1[0], w1[1], w1[2], w1[3]};
        u32x4 t11 = {w1[4], w1[5], w1[6], w1[7]};
        bf16x8 p00 = __builtin_bit_cast(bf16x8, t00);
        bf16x8 p01 = __builtin_bit_cast(bf16x8, t01);
        bf16x8 p10 = __builtin_bit_cast(bf16x8, t10);
        bf16x8 p11 = __builtin_bit_cast(bf16x8, t11);

        // O += P . V ; V-frags shared across both q-blocks
        #pragma unroll
        for (int db = 0; db < 4; ++db) {
            bf16x8 vb0 = *(const bf16x8*)((const char*)Vl +
                swzo(db * 32 + lr, (ksub + lg * 8) * 2));
            bf16x8 vb1 = *(const bf16x8*)((const char*)Vl +
                swzo(db * 32 + lr, (ksub + 16 + lg * 8) * 2));
            acc[0][db] = MFMA32(p00, vb0, acc[0][db]);
            acc[0][db] = MFMA32(p01, vb1, acc[0][db]);
            acc[1][db] = MFMA32(p10, vb0, acc[1][db]);
            acc[1][db] = MFMA32(p11, vb1, acc[1][db]);
        }
    }

    // epilogue: C layout col=lane&31=d, row=(r&3)+8*(r>>2)+4*lg = q offset
    float* Ob = Out + (size_t)b * S_LEN * DIM;
    #pragma unroll
    for (int qb = 0; qb < 2; ++qb)
        #pragma unroll
        for (int db = 0; db < 4; ++db)
            #pragma unroll
            for (int r = 0; r < 16; ++r) {
                int q = qw + qb * 32 + (r & 3) + ((r >> 2) << 3) + (lg << 2);
                int d = db * 32 + lr;
                atomicAdd(Ob + (size_t)q * DIM + d, acc[qb][db][r]);
            }
}

extern "C" void kernel_launch(void* const* d_in, const int* in_sizes, int n_in,
                              void* d_out, int out_size, void* d_ws, size_t ws_size,
                              hipStream_t stream) {
    const float* Q = (const float*)d_in[0];
    const float* K = (const float*)d_in[1];
    const float* V = (const float*)d_in[2];
    float* Out = (float*)d_out;

    size_t planeBytes = (size_t)NB * S_LEN * DIM * sizeof(bf16_t); // 4 MB
    if (ws_size < 3 * planeBytes) return;   // need 12 MB scratch
    char* wsb = (char*)d_ws;
    bf16_t* Qr = (bf16_t*)wsb;
    bf16_t* Kr = (bf16_t*)(wsb + planeBytes);
    bf16_t* Vt = (bf16_t*)(wsb + 2 * planeBytes);

    hipMemsetAsync(d_out, 0, (size_t)NB * S_LEN * DIM * sizeof(float), stream);

    prep_kernel<<<ROPE_BLKS + (S_LEN / 64) * NB, 256, 0, stream>>>(Q, K, V, Qr, Kr, Vt);

    int chunks = 0;
    for (int i = 0; i < NQT; ++i) chunks += 2 * (i + 1);   // 272 per batch
    attn_main_kernel<<<NB * chunks, 256, 0, stream>>>(Qr, Kr, Vt, Out);
}

// Round 4
// 38.249 us; speedup vs baseline: 4.7199x; 4.7199x over previous
//
#include <hip/hip_runtime.h>
#include <hip/hip_bf16.h>

#define S_LEN 4096
#define DIM   128
#define NB    4
#define L_CHUNK 128
#define NCH   (S_LEN / L_CHUNK)      // 32 chunks per batch
#define ROPE_BLKS (NB * S_LEN / 4)   // 4096
#define TR_BLKS   (NB * S_LEN / 64)  // 256
#define NQT   (S_LEN / 256)          // fallback: 16 q-tiles per batch
#define CH_FB 3                      // fallback split-K

typedef __bf16 bf16_t;
typedef __attribute__((ext_vector_type(8)))  __bf16       bf16x8;
typedef __attribute__((ext_vector_type(16))) float        f32x16;
typedef __attribute__((ext_vector_type(4)))  unsigned int u32x4;

#define MFMA32(a, b, c) __builtin_amdgcn_mfma_f32_32x32x16_bf16((a), (b), (c), 0, 0, 0)
#define CVTPK(d, a, b) asm("v_cvt_pk_bf16_f32 %0, %1, %2" : "=v"(d) : "v"(a), "v"(b))
// vdst HIGH lanes <-> vsrc LOW lanes (verified round 2)
#define PSWAP(d, s)    asm("v_permlane32_swap_b32 %0, %1" : "+v"(d), "+v"(s))

__device__ __forceinline__ unsigned swzo(int row, int colByte) {
    return (unsigned)(row * 256 + (colByte ^ ((row & 15) << 4)));
}

__device__ __forceinline__ void cvt_swap(const f32x16& s, unsigned int w[8]) {
    CVTPK(w[0], s[0],  s[1]);  CVTPK(w[1], s[2],  s[3]);
    CVTPK(w[2], s[4],  s[5]);  CVTPK(w[3], s[6],  s[7]);
    CVTPK(w[4], s[8],  s[9]);  CVTPK(w[5], s[10], s[11]);
    CVTPK(w[6], s[12], s[13]); CVTPK(w[7], s[14], s[15]);
    PSWAP(w[0], w[2]); PSWAP(w[1], w[3]);
    PSWAP(w[4], w[6]); PSWAP(w[5], w[7]);
}

// ---------------- prep: RoPE(Q,K)->Qr,Kr ; V->Vt ; RoPE(K)->KrT ----------------
__global__ void prep_kernel(const float* __restrict__ Q,
                            const float* __restrict__ K,
                            const float* __restrict__ V,
                            bf16_t* __restrict__ Qr,
                            bf16_t* __restrict__ Kr,
                            bf16_t* __restrict__ Vt,
                            bf16_t* __restrict__ KrT) {
    int bid = blockIdx.x;
    int t   = threadIdx.x;
    if (bid < ROPE_BLKS) {
        int i   = t & 63;
        int row = bid * 4 + (t >> 6);
        int s   = row & (S_LEN - 1);
        size_t base = (size_t)row * DIM;
        float e       = -(float)i * (13.287712379549449f / 64.0f);
        float inv_rev = exp2f(e) * 0.15915494309189535f;
        float rev = (float)s * inv_rev;
        float fr  = rev - floorf(rev);
        float c  = __builtin_amdgcn_cosf(fr);
        float sn = __builtin_amdgcn_sinf(fr);
        float q1 = Q[base + i], q2 = Q[base + i + 64];
        float k1 = K[base + i], k2 = K[base + i + 64];
        Qr[base + i]      = (bf16_t)(q1 * c - q2 * sn);
        Qr[base + i + 64] = (bf16_t)(q2 * c + q1 * sn);
        Kr[base + i]      = (bf16_t)(k1 * c - k2 * sn);
        Kr[base + i + 64] = (bf16_t)(k2 * c + k1 * sn);
    } else if (bid < ROPE_BLKS + TR_BLKS) {
        int idx = bid - ROPE_BLKS;
        int b   = idx >> 6;
        int s0  = (idx & 63) * 64;
        int d   = t >> 1;
        int sh  = (t & 1) * 32;
        const float* vb = V + (size_t)b * S_LEN * DIM;
        bf16_t* ob = Vt + ((size_t)b * DIM + d) * S_LEN;
        #pragma unroll
        for (int j8 = 0; j8 < 4; ++j8) {
            bf16x8 u;
            #pragma unroll
            for (int e2 = 0; e2 < 8; ++e2) {
                int s = s0 + sh + j8 * 8 + e2;
                u[e2] = (bf16_t)vb[(size_t)s * DIM + d];
            }
            *(bf16x8*)(ob + s0 + sh + j8 * 8) = u;
        }
    } else {
        int idx = bid - ROPE_BLKS - TR_BLKS;
        int b   = idx >> 6;
        int s0  = (idx & 63) * 64;
        int d   = t >> 1;
        int sh  = (t & 1) * 32;
        const float* kb = K + (size_t)b * S_LEN * DIM;
        bf16_t* ob = KrT + ((size_t)b * DIM + d) * S_LEN;
        int i = d & 63;
        float e       = -(float)i * (13.287712379549449f / 64.0f);
        float inv_rev = exp2f(e) * 0.15915494309189535f;
        float sgn = (d < 64) ? -1.f : 1.f;
        #pragma unroll
        for (int j8 = 0; j8 < 4; ++j8) {
            bf16x8 u;
            #pragma unroll
            for (int e2 = 0; e2 < 8; ++e2) {
                int s = s0 + sh + j8 * 8 + e2;
                float rev = (float)s * inv_rev;
                float fr  = rev - floorf(rev);
                float c2  = __builtin_amdgcn_cosf(fr);
                float sn2 = __builtin_amdgcn_sinf(fr);
                float k1 = kb[(size_t)s * DIM + d];
                float k2 = kb[(size_t)s * DIM + (d ^ 64)];
                u[e2] = (bf16_t)(k1 * c2 + sgn * k2 * sn2);
            }
            *(bf16x8*)(ob + s0 + sh + j8 * 8) = u;
        }
    }
}

// ---------------- stage1: G[b][c][dv][dk] = sum_k V[k][dv]*Kr[k][dk] ----------------
__launch_bounds__(256, 2)
__global__ void stage1_kernel(const bf16_t* __restrict__ KrT,
                              const bf16_t* __restrict__ Vt,
                              bf16_t* __restrict__ G) {
    __shared__ bf16_t Ks1[128 * 128];  // KrT rows (dk)
    __shared__ bf16_t Vs1[128 * 128];  // Vt rows (dv)
    int b = blockIdx.x >> 5;
    int c = blockIdx.x & 31;
    int tid = threadIdx.x, w = tid >> 6, lane = tid & 63;
    int lr = lane & 31, lg = lane >> 5;
    int k0 = c * L_CHUNK;
    const bf16_t* Kb = KrT + (size_t)b * DIM * S_LEN;
    const bf16_t* Vb = Vt  + (size_t)b * DIM * S_LEN;
    #pragma unroll
    for (int j = 0; j < 8; ++j) {
        int idx = tid + j * 256;
        int row = idx >> 4, slot = idx & 15;
        u32x4 kd = *(const u32x4*)(Kb + (size_t)row * S_LEN + k0 + slot * 8);
        *(u32x4*)((char*)Ks1 + swzo(row, slot * 16)) = kd;
        u32x4 vd = *(const u32x4*)(Vb + (size_t)row * S_LEN + k0 + slot * 8);
        *(u32x4*)((char*)Vs1 + swzo(row, slot * 16)) = vd;
    }
    __syncthreads();

    f32x16 acc[4];
    #pragma unroll
    for (int db = 0; db < 4; ++db)
        #pragma unroll
        for (int r = 0; r < 16; ++r) acc[db][r] = 0.f;

    #pragma unroll
    for (int s = 0; s < 8; ++s) {
        bf16x8 af = *(const bf16x8*)((const char*)Vs1 +
            swzo(32 * w + lr, (s * 16 + lg * 8) * 2));
        #pragma unroll
        for (int db = 0; db < 4; ++db) {
            bf16x8 bfr = *(const bf16x8*)((const char*)Ks1 +
                swzo(32 * db + lr, (s * 16 + lg * 8) * 2));
            acc[db] = MFMA32(af, bfr, acc[db]);
        }
    }
    bf16_t* Gc = G + ((size_t)b * NCH + c) * DIM * DIM;
    #pragma unroll
    for (int db = 0; db < 4; ++db)
        #pragma unroll
        for (int r = 0; r < 16; ++r) {
            int dv = 32 * w + (r & 3) + ((r >> 2) << 3) + (lg << 2);
            Gc[(size_t)dv * DIM + 32 * db + lr] = (bf16_t)acc[db][r];
        }
}

// ---------------- stage2: in-place exclusive prefix over chunks ----------------
__global__ void stage2_kernel(bf16_t* __restrict__ G) {
    int b = blockIdx.x >> 6;
    int idx = (blockIdx.x & 63) * 256 + threadIdx.x;  // 0..16383
    bf16_t* p = G + (size_t)b * NCH * DIM * DIM + idx;
    float run = 0.f;
    for (int c = 0; c < NCH; ++c) {
        float v = (float)p[(size_t)c * DIM * DIM];
        p[(size_t)c * DIM * DIM] = (bf16_t)run;
        run += v;
    }
}

// ---------------- stage3: O = Q*G_pre + tril(Q Kc^T) Vc  (plain stores) ----------------
__launch_bounds__(256, 1)
__global__ void stage3_kernel(const bf16_t* __restrict__ Qr,
                              const bf16_t* __restrict__ Kr,
                              const bf16_t* __restrict__ Vt,
                              const bf16_t* __restrict__ Gp,
                              float* __restrict__ Out) {
    __shared__ bf16_t Ks[128 * 128];
    __shared__ bf16_t Vs[128 * 128];
    __shared__ bf16_t Gs[128 * 128];
    int b = blockIdx.x >> 5;
    int c = blockIdx.x & 31;
    int tid = threadIdx.x, w = tid >> 6, lane = tid & 63;
    int lr = lane & 31, lg = lane >> 5;
    int q0 = c * L_CHUNK;
    const bf16_t* Qb = Qr + (size_t)b * S_LEN * DIM;
    const bf16_t* Kb = Kr + (size_t)b * S_LEN * DIM;
    const bf16_t* Vb = Vt + (size_t)b * DIM * S_LEN;
    const bf16_t* Gb = Gp + ((size_t)b * NCH + c) * DIM * DIM;

    bf16x8 qf[8];
    #pragma unroll
    for (int s2 = 0; s2 < 8; ++s2)
        qf[s2] = *(const bf16x8*)(Qb + (size_t)(q0 + 32 * w + lr) * DIM
                                  + s2 * 16 + lg * 8);

    #pragma unroll
    for (int j = 0; j < 8; ++j) {
        int idx = tid + j * 256;
        int row = idx >> 4, slot = idx & 15;
        u32x4 kd = *(const u32x4*)(Kb + (size_t)(q0 + row) * DIM + slot * 8);
        *(u32x4*)((char*)Ks + swzo(row, slot * 16)) = kd;
        u32x4 vd = *(const u32x4*)(Vb + (size_t)row * S_LEN + q0 + slot * 8);
        *(u32x4*)((char*)Vs + swzo(row, slot * 16)) = vd;
    }
    if (c > 0) {
        #pragma unroll
        for (int j = 0; j < 8; ++j) {
            int idx = tid + j * 256;
            int row = idx >> 4, slot = idx & 15;
            u32x4 gd = *(const u32x4*)(Gb + (size_t)row * DIM + slot * 8);
            *(u32x4*)((char*)Gs + swzo(row, slot * 16)) = gd;
        }
    }
    __syncthreads();

    f32x16 acc[4];
    #pragma unroll
    for (int db = 0; db < 4; ++db)
        #pragma unroll
        for (int r = 0; r < 16; ++r) acc[db][r] = 0.f;

    // part A: O += Q . G_pre   (A = qf rows of Q; B = rows d of G: G[d][d'])
    if (c > 0) {
        #pragma unroll
        for (int s2 = 0; s2 < 8; ++s2) {
            #pragma unroll
            for (int db = 0; db < 4; ++db) {
                bf16x8 gfr = *(const bf16x8*)((const char*)Gs +
                    swzo(32 * db + lr, (s2 * 16 + lg * 8) * 2));
                acc[db] = MFMA32(qf[s2], gfr, acc[db]);
            }
        }
    }

    // intra: causal within the diagonal chunk (swapped QK^T, cvt_pk+permlane P)
    for (int g = 0; g <= w; ++g) {
        int ksub = g * 32;
        f32x16 sa;
        #pragma unroll
        for (int r = 0; r < 16; ++r) sa[r] = 0.f;
        #pragma unroll
        for (int s2 = 0; s2 < 8; ++s2) {
            bf16x8 af = *(const bf16x8*)((const char*)Ks +
                swzo(ksub + lr, (s2 * 16 + lg * 8) * 2));
            sa = MFMA32(af, qf[s2], sa);
        }
        if (g == w) {  // diagonal sub-tile: zero k > q
            #pragma unroll
            for (int r = 0; r < 16; ++r) {
                int crow = (r & 3) + ((r >> 2) << 3) + (lg << 2);
                sa[r] = (crow > lr) ? 0.f : sa[r];
            }
        }
        unsigned int wv[8];
        cvt_swap(sa, wv);
        u32x4 tA = {wv[0], wv[1], wv[2], wv[3]};
        u32x4 tB = {wv[4], wv[5], wv[6], wv[7]};
        bf16x8 pA = __builtin_bit_cast(bf16x8, tA);
        bf16x8 pB = __builtin_bit_cast(bf16x8, tB);
        #pragma unroll
        for (int db = 0; db < 4; ++db) {
            bf16x8 v0 = *(const bf16x8*)((const char*)Vs +
                swzo(32 * db + lr, (ksub + lg * 8) * 2));
            bf16x8 v1 = *(const bf16x8*)((const char*)Vs +
                swzo(32 * db + lr, (ksub + 16 + lg * 8) * 2));
            acc[db] = MFMA32(pA, v0, acc[db]);
            acc[db] = MFMA32(pB, v1, acc[db]);
        }
    }

    float* Ob = Out + (size_t)b * S_LEN * DIM;
    #pragma unroll
    for (int db = 0; db < 4; ++db)
        #pragma unroll
        for (int r = 0; r < 16; ++r) {
            int q = q0 + 32 * w + (r & 3) + ((r >> 2) << 3) + (lg << 2);
            Ob[(size_t)q * DIM + 32 * db + lr] = acc[db][r];
        }
}

// ---------------- fallback (ws < 20MB): round-2 verified atomic path ----------------
__launch_bounds__(256, 2)
__global__ void attn_fb_kernel(const bf16_t* __restrict__ Qr,
                               const bf16_t* __restrict__ Kr,
                               const bf16_t* __restrict__ Vt,
                               float* __restrict__ Out) {
    __shared__ bf16_t Kt[128 * 128];
    __shared__ bf16_t Vl[128 * 128];
    int b = blockIdx.x & 3;
    int t = blockIdx.x >> 2;
    int qt = 0, c0 = 0;
    for (int i2 = NQT - 1; i2 >= 0; --i2) {
        int n = (2 * (i2 + 1) + CH_FB - 1) / CH_FB;
        if (t < n) { qt = i2; c0 = t; break; }
        t -= n;
    }
    int nkt   = 2 * (qt + 1);
    int kt_lo = c0 * CH_FB;
    int kt_hi = min(kt_lo + CH_FB, nkt);
    bool single = ((nkt + CH_FB - 1) / CH_FB) == 1;

    int tid = threadIdx.x, w = tid >> 6, lane = tid & 63;
    int lr = lane & 31, lg = lane >> 5;
    int qw = qt * 256 + w * 64;
    const bf16_t* Qb = Qr + (size_t)b * S_LEN * DIM;
    const bf16_t* Kb = Kr + (size_t)b * S_LEN * DIM;
    const bf16_t* Vb = Vt + (size_t)b * DIM * S_LEN;

    bf16x8 qf[2][8];
    #pragma unroll
    for (int qb = 0; qb < 2; ++qb)
        #pragma unroll
        for (int s2 = 0; s2 < 8; ++s2)
            qf[qb][s2] = *(const bf16x8*)(Qb + (size_t)(qw + qb * 32 + lr) * DIM
                                          + s2 * 16 + lg * 8);
    f32x16 acc[2][4];
    #pragma unroll
    for (int qb = 0; qb < 2; ++qb)
        #pragma unroll
        for (int db = 0; db < 4; ++db)
            #pragma unroll
            for (int r = 0; r < 16; ++r) acc[qb][db][r] = 0.f;

    for (int kt = kt_lo; kt < kt_hi; ++kt) {
        int kbase = kt * 128;
        #pragma unroll
        for (int j = 0; j < 8; ++j) {
            int idx = tid + j * 256;
            int row = idx >> 4, slot = idx & 15;
            u32x4 kd = *(const u32x4*)(Kb + (size_t)(kbase + row) * DIM + slot * 8);
            *(u32x4*)((char*)Kt + swzo(row, slot * 16)) = kd;
            u32x4 vd = *(const u32x4*)(Vb + (size_t)row * S_LEN + kbase + slot * 8);
            *(u32x4*)((char*)Vl + swzo(row, slot * 16)) = vd;
        }
        __syncthreads();
        #pragma unroll
        for (int kb = 0; kb < 4; ++kb) {
            int ksub = kb * 32;
            int kmin = kbase + ksub;
            if (kmin > qw + 63) break;
            bool do0 = (kmin <= qw + 31);
            f32x16 s0, s1;
            #pragma unroll
            for (int r = 0; r < 16; ++r) { s0[r] = 0.f; s1[r] = 0.f; }
            #pragma unroll
            for (int h = 0; h < 2; ++h) {
                bf16x8 af[4];
                #pragma unroll
                for (int s2 = 0; s2 < 4; ++s2)
                    af[s2] = *(const bf16x8*)((const char*)Kt +
                        swzo(ksub + lr, (h * 64 + s2 * 16 + lg * 8) * 2));
                #pragma unroll
                for (int s2 = 0; s2 < 4; ++s2) {
                    if (do0) s0 = MFMA32(af[s2], qf[0][h * 4 + s2], s0);
                    s1 = MFMA32(af[s2], qf[1][h * 4 + s2], s1);
                }
            }
            if (kmin + 31 > qw) {
                #pragma unroll
                for (int r = 0; r < 16; ++r) {
                    int kg = kmin + (r & 3) + ((r >> 2) << 3) + (lg << 2);
                    s0[r] = (kg > qw + lr)      ? 0.f : s0[r];
                    s1[r] = (kg > qw + 32 + lr) ? 0.f : s1[r];
                }
            }
            unsigned int w0[8], w1[8];
            cvt_swap(s0, w0);
            cvt_swap(s1, w1);
            u32x4 t00 = {w0[0], w0[1], w0[2], w0[3]};
            u32x4 t01 = {w0[4], w0[5], w0[6], w0[7]};
            u32x4 t10 = {w1[0], w1[1], w1[2], w1[3]};
            u32x4 t11 = {w1[4], w1[5], w1[6], w1[7]};
            bf16x8 p00 = __builtin_bit_cast(bf16x8, t00);
            bf16x8 p01 = __builtin_bit_cast(bf16x8, t01);
            bf16x8 p10 = __builtin_bit_cast(bf16x8, t10);
            bf16x8 p11 = __builtin_bit_cast(bf16x8, t11);
            #pragma unroll
            for (int db = 0; db < 4; ++db) {
                bf16x8 vb0 = *(const bf16x8*)((const char*)Vl +
                    swzo(db * 32 + lr, (ksub + lg * 8) * 2));
                bf16x8 vb1 = *(const bf16x8*)((const char*)Vl +
                    swzo(db * 32 + lr, (ksub + 16 + lg * 8) * 2));
                if (do0) {
                    acc[0][db] = MFMA32(p00, vb0, acc[0][db]);
                    acc[0][db] = MFMA32(p01, vb1, acc[0][db]);
                }
                acc[1][db] = MFMA32(p10, vb0, acc[1][db]);
                acc[1][db] = MFMA32(p11, vb1, acc[1][db]);
            }
        }
        __syncthreads();
    }
    float* Ob = Out + (size_t)b * S_LEN * DIM;
    #pragma unroll
    for (int qb = 0; qb < 2; ++qb)
        #pragma unroll
        for (int db = 0; db < 4; ++db)
            #pragma unroll
            for (int r = 0; r < 16; ++r) {
                int q = qw + qb * 32 + (r & 3) + ((r >> 2) << 3) + (lg << 2);
                int d = db * 32 + lr;
                float v = acc[qb][db][r];
                float* p = Ob + (size_t)q * DIM + d;
                if (single) *p = v; else atomicAdd(p, v);
            }
}

extern "C" void kernel_launch(void* const* d_in, const int* in_sizes, int n_in,
                              void* d_out, int out_size, void* d_ws, size_t ws_size,
                              hipStream_t stream) {
    const float* Q = (const float*)d_in[0];
    const float* K = (const float*)d_in[1];
    const float* V = (const float*)d_in[2];
    float* Out = (float*)d_out;

    size_t plane  = (size_t)NB * S_LEN * DIM * sizeof(bf16_t);      // 4 MB
    size_t gbytes = (size_t)NB * NCH * DIM * DIM * sizeof(bf16_t);  // 4 MB
    char* wsb = (char*)d_ws;
    bf16_t* Qr = (bf16_t*)wsb;
    bf16_t* Kr = (bf16_t*)(wsb + plane);
    bf16_t* Vt = (bf16_t*)(wsb + 2 * plane);

    if (ws_size >= 4 * plane + gbytes) {
        // chunked-scan path (no atomics, no memset)
        bf16_t* KrT = (bf16_t*)(wsb + 3 * plane);
        bf16_t* G   = (bf16_t*)(wsb + 4 * plane);
        prep_kernel<<<ROPE_BLKS + 2 * TR_BLKS, 256, 0, stream>>>(Q, K, V, Qr, Kr, Vt, KrT);
        stage1_kernel<<<NB * NCH, 256, 0, stream>>>(KrT, Vt, G);
        stage2_kernel<<<NB * 64, 256, 0, stream>>>(G);
        stage3_kernel<<<NB * NCH, 256, 0, stream>>>(Qr, Kr, Vt, G, Out);
    } else if (ws_size >= 3 * plane) {
        // fallback: round-2 verified atomic split-K path
        hipMemsetAsync(d_out, 0, (size_t)NB * S_LEN * DIM * sizeof(float), stream);
        prep_kernel<<<ROPE_BLKS + TR_BLKS, 256, 0, stream>>>(Q, K, V, Qr, Kr, Vt, Vt);
        int chunks = 0;
        for (int i = 0; i < NQT; ++i) chunks += (2 * (i + 1) + CH_FB - 1) / CH_FB;
        attn_fb_kernel<<<NB * chunks, 256, 0, stream>>>(Qr, Kr, Vt, Out);
    }
}